// Round 1
// baseline (122.763 us; speedup 1.0000x reference)
//
#include <hip/hip_runtime.h>
#include <math.h>
#include <stdint.h>

#define BATCH 64
#define SEQ   101
#define HID   512
#define NKQ   100      // N*K
#define KCLS  10
#define INV_TEMP 0.04419417382415922f   // 1/sqrt(512)

typedef short bf16x8 __attribute__((ext_vector_type(8)));
typedef float f32x4  __attribute__((ext_vector_type(4)));

// truncation split: x == hi + lo to ~2^-17 rel
__device__ inline void split_bf16(float x, short& hi, short& lo) {
    uint32_t u = __builtin_bit_cast(uint32_t, x);
    hi = (short)(u >> 16);
    float hf = __builtin_bit_cast(float, u & 0xFFFF0000u);
    float l  = x - hf;
    lo = (short)(__builtin_bit_cast(uint32_t, l) >> 16);
}
// round-to-nearest-even bf16 (single-plane operands)
__device__ inline short rtn_bf16(float x) {
    uint32_t u = __builtin_bit_cast(uint32_t, x);
    return (short)((u + 0x7FFFu + ((u >> 16) & 1u)) >> 16);
}

// ---------------------------------------------------------------------------
// Fully fused: QK^T + softmax + weighted PV + epilogue in ONE kernel.
// grid 448 flat: b = id&63 (XCD affinity: same-b blocks share an XCD's L2 for
// k/v reuse), i-tile = id>>6 (16 rows). 512 thr = 8 waves.
// Probabilities live in LDS sc[16][132] between phases -- no workspace at all.
//
// LDS pool (bytes), phase-1 and phase-3 regions overlap (union):
//   phase1: khi[128][72]sh @0      (18432)
//           qhi[16][72]sh  @18432  ( 2304)
//           qlo[16][72]sh  @20736  ( 2304)   -> 23040 used
//   phase3: vraw[64][132]f @0      (33792)
//           vth[128][72]sh @33792  (18432)
//           vtl[128][72]sh @52224  (18432)   -> 70656 used
//   persistent: sc[16][132]f (8448)
// total static = 70656 + 8448 = 79104 B -> 2 blocks/CU (158208 <= 163840)
// ---------------------------------------------------------------------------
#define KCH 64
#define KST 72    // k/q LDS row stride (shorts): 144 B, 16B-aligned, 2-way max on m-reads
#define VST 72    // vth/vtl row stride (shorts): 64 j cols + 8 pad
#define VRS 132   // vraw row stride (floats): 128 h cols + 4 pad

#define OFF_QHI 18432
#define OFF_QLO 20736
#define OFF_VTH 33792
#define OFF_VTL 52224
#define POOLSZ  70656

__global__ __launch_bounds__(512, 4)
void fused_attn(const float* __restrict__ q, const float* __restrict__ k,
                const float* __restrict__ v, const float* __restrict__ aw,
                float* __restrict__ out, float* __restrict__ attn) {
    __shared__ __align__(16) char pool[POOLSZ];
    __shared__ __align__(16) float sc[16][132];
    short (*khi)[KST]  = (short(*)[KST])(pool);
    short (*qhi)[KST]  = (short(*)[KST])(pool + OFF_QHI);
    short (*qlo)[KST]  = (short(*)[KST])(pool + OFF_QLO);
    float (*vraw)[VRS] = (float(*)[VRS])(pool);
    short (*vth)[VST]  = (short(*)[VST])(pool + OFF_VTH);
    short (*vtl)[VST]  = (short(*)[VST])(pool + OFF_VTL);

    const int b   = blockIdx.x & 63;
    const int i0  = (blockIdx.x >> 6) * 16;
    const int tid = threadIdx.x;
    const int wv  = tid >> 6, lane = tid & 63;
    const int m   = lane & 15;
    const int kq  = (lane >> 4) * 8;
    const int rq  = (lane >> 4) * 4;
    const int j0w = wv * 16;

    const float* qb = q + (size_t)b * SEQ * HID;
    const float* kb = k + (size_t)b * SEQ * HID;
    const float* vb = v + (size_t)b * SEQ * HID;

    // ---------------- phase 1: QK^T (LDS-staged bf16 hi/lo) ----------------
    f32x4 acc = {};
    for (int kc = 0; kc < HID; kc += KCH) {
        // stage k chunk: 128 rows x 64 floats = 2048 float4, 4 per thread
        #pragma unroll
        for (int s = 0; s < 4; ++s) {
            const int f = tid + s * 512;
            const int r = f >> 4, c = (f & 15) << 2;
            float4 x = make_float4(0.f, 0.f, 0.f, 0.f);
            if (r < SEQ) x = *(const float4*)(kb + (size_t)r * HID + kc + c);
            short4 hv;
            hv.x = rtn_bf16(x.x); hv.y = rtn_bf16(x.y);
            hv.z = rtn_bf16(x.z); hv.w = rtn_bf16(x.w);
            *(short4*)&khi[r][c] = hv;
        }
        // stage q chunk: 16 rows x 64 floats, threads [0,256)
        if (tid < 256) {
            const int r = tid >> 4, c = (tid & 15) << 2;
            const int gi = i0 + r;
            float4 x = make_float4(0.f, 0.f, 0.f, 0.f);
            if (gi < SEQ) x = *(const float4*)(qb + (size_t)gi * HID + kc + c);
            short4 hv, lv;
            split_bf16(x.x, hv.x, lv.x);
            split_bf16(x.y, hv.y, lv.y);
            split_bf16(x.z, hv.z, lv.z);
            split_bf16(x.w, hv.w, lv.w);
            *(short4*)&qhi[r][c] = hv;
            *(short4*)&qlo[r][c] = lv;
        }
        __syncthreads();
        #pragma unroll
        for (int ks = 0; ks < KCH; ks += 32) {
            const bf16x8 qH = *(const bf16x8*)&qhi[m][ks + kq];
            const bf16x8 qL = *(const bf16x8*)&qlo[m][ks + kq];
            const bf16x8 kH = *(const bf16x8*)&khi[j0w + m][ks + kq];
            acc = __builtin_amdgcn_mfma_f32_16x16x32_bf16(qH, kH, acc, 0, 0, 0);
            acc = __builtin_amdgcn_mfma_f32_16x16x32_bf16(qL, kH, acc, 0, 0, 0);
        }
        __syncthreads();
    }
    #pragma unroll
    for (int r = 0; r < 4; ++r)
        sc[rq + r][j0w + m] = acc[r];
    __syncthreads();

    // ---------------- phase 2: softmax; normalized P stays in sc -----------
    {
        const int row = tid >> 5, t32 = tid & 31;
        const int gi  = i0 + row;
        float mx = -1e30f;
        for (int j = t32; j < SEQ; j += 32) {
            float s = sc[row][j] * INV_TEMP;
            sc[row][j] = s;
            mx = fmaxf(mx, s);
        }
        #pragma unroll
        for (int off = 1; off < 32; off <<= 1) mx = fmaxf(mx, __shfl_xor(mx, off));
        float sum = 0.f;
        for (int j = t32; j < SEQ; j += 32) {
            float e = __expf(sc[row][j] - mx);
            sc[row][j] = e;
            sum += e;
        }
        #pragma unroll
        for (int off = 1; off < 32; off <<= 1) sum += __shfl_xor(sum, off);
        const float inv = 1.f / sum;
        float* arow = attn + ((size_t)b * SEQ + gi) * SEQ;
        for (int j = t32; j < SEQ; j += 32) {
            float a = sc[row][j] * inv;
            sc[row][j] = a;                 // write-back: PV reads P from LDS
            if (gi < SEQ) arow[j] = a;      // tuple output
        }
        for (int j = SEQ + t32; j < 128; j += 32) sc[row][j] = 0.f;  // pad cols
    }
    __syncthreads();

    // ---------------- A fragments (hoisted once per wave) -------------------
    int ai = i0 + m; if (ai > NKQ) ai = NKQ;      // clamp for garbage rows
    const int ci = ai / KCLS;
    uint32_t mbits = 0;                           // same-class mask, bit ks*8+e
    #pragma unroll
    for (int ks = 0; ks < 4; ++ks)
        #pragma unroll
        for (int e = 0; e < 8; ++e)
            if (((ks * 32 + kq + e) / KCLS) == ci) mbits |= (1u << (ks * 8 + e));
    bf16x8 Ah[4], Al[4];
    #pragma unroll
    for (int ks = 0; ks < 4; ++ks) {
        const f32x4 u0 = *(const f32x4*)&sc[m][ks * 32 + kq];
        const f32x4 u1 = *(const f32x4*)&sc[m][ks * 32 + kq + 4];
        const float x[8] = {u0[0], u0[1], u0[2], u0[3], u1[0], u1[1], u1[2], u1[3]};
        #pragma unroll
        for (int e = 0; e < 8; ++e) {
            short h, l; split_bf16(x[e], h, l);
            Ah[ks][e] = h; Al[ks][e] = l;
        }
    }

    // ---------------- phase 3: PV + epilogue, 4 h-chunks of 128 -------------
    for (int hc = 0; hc < 4; ++hc) {
        const int hbase = hc << 7;
        f32x4 T = {}, U = {};
        #pragma unroll
        for (int half = 0; half < 2; ++half) {
            __syncthreads();   // prev MFMA done (vth reusable), prev convert done (vraw reusable)
            // stage v: 64 j-rows x 128 h, coalesced float4
            #pragma unroll
            for (int s = 0; s < 4; ++s) {
                const int f = tid + s * 512;
                const int j = f >> 5, h4 = (f & 31) << 2;
                const int jg = half * 64 + j;
                float4 x = make_float4(0.f, 0.f, 0.f, 0.f);
                if (jg < SEQ) x = *(const float4*)(vb + (size_t)jg * HID + hbase + h4);
                *(float4*)&vraw[j][h4] = x;
            }
            __syncthreads();
            // transpose-convert to bf16 hi/lo: short4 along j
            #pragma unroll
            for (int s = 0; s < 4; ++s) {
                const int it = tid + s * 512;
                const int h = it & 127, jl = (it >> 7) << 2;
                short4 hv, lv;
                split_bf16(vraw[jl + 0][h], hv.x, lv.x);
                split_bf16(vraw[jl + 1][h], hv.y, lv.y);
                split_bf16(vraw[jl + 2][h], hv.z, lv.z);
                split_bf16(vraw[jl + 3][h], hv.w, lv.w);
                *(short4*)&vth[h][jl] = hv;
                *(short4*)&vtl[h][jl] = lv;
            }
            __syncthreads();
            // pure LDS->MFMA
            #pragma unroll
            for (int ksl = 0; ksl < 2; ++ksl) {
                const int ks = half * 2 + ksl;
                const bf16x8 Bh = *(const bf16x8*)&vth[j0w + m][ksl * 32 + kq];
                const bf16x8 Bl = *(const bf16x8*)&vtl[j0w + m][ksl * 32 + kq];
                bf16x8 Mh;
                #pragma unroll
                for (int e = 0; e < 8; ++e)
                    Mh[e] = (mbits & (1u << (ks * 8 + e))) ? Ah[ks][e] : (short)0;
                T = __builtin_amdgcn_mfma_f32_16x16x32_bf16(Ah[ks], Bh, T, 0, 0, 0);
                T = __builtin_amdgcn_mfma_f32_16x16x32_bf16(Ah[ks], Bl, T, 0, 0, 0);
                T = __builtin_amdgcn_mfma_f32_16x16x32_bf16(Al[ks], Bh, T, 0, 0, 0);
                U = __builtin_amdgcn_mfma_f32_16x16x32_bf16(Mh,     Bh, U, 0, 0, 0);
            }
        }
        // epilogue for this h-chunk (reads only sc + globals; no LDS hazard)
        const int h = hbase + j0w + m;
        const float w0 = aw[0 * HID + h], w1 = aw[1 * HID + h], w2 = aw[2 * HID + h];
        const float w3 = aw[3 * HID + h], w4 = aw[4 * HID + h], w5 = aw[5 * HID + h];
        const float vN = vb[(size_t)NKQ * HID + h];
        #pragma unroll
        for (int r = 0; r < 4; ++r) {
            const int i = i0 + rq + r;
            if (i >= SEQ) continue;
            const int il = rq + r;
            const float t = T[r], u = U[r];
            const float aiN = sc[il][NKQ];
            float o;
            if (i < NKQ) {
                const float aii = sc[il][i];
                const float vi  = vb[(size_t)i * HID + h];
                o = w2 * t + (w1 - w2) * u + (w0 - w1) * aii * vi + (w3 - w2) * aiN * vN;
            } else {
                o = w4 * t + (w5 - w4) * aiN * vN;
            }
            out[((size_t)b * SEQ + i) * HID + h] = o;
        }
    }
}

extern "C" void kernel_launch(void* const* d_in, const int* in_sizes, int n_in,
                              void* d_out, int out_size, void* d_ws, size_t ws_size,
                              hipStream_t stream) {
    const float* q  = (const float*)d_in[0];
    const float* k  = (const float*)d_in[1];
    const float* v  = (const float*)d_in[2];
    const float* aw = (const float*)d_in[3];
    float* out  = (float*)d_out;
    float* attn = out + (size_t)BATCH * SEQ * HID;   // tuple output: [out | attn]
    (void)d_ws; (void)ws_size;

    fused_attn<<<dim3(448), dim3(512), 0, stream>>>(q, k, v, aw, out, attn);
}